// Round 12
// baseline (57.826 us; speedup 1.0000x reference)
//
#include <hip/hip_runtime.h>

#define BATCH   4
#define CIN     64
#define NNODES  4096
#define NEDGES  131072
#define COUT    63
#define NPB     16          // nodes owned per block in k_main
#define CAP     128         // per-node bucket capacity (deg ~Poisson(32), max ~70)
#define NT      1024        // 16 waves/block

// ---------------- k0: transpose x (b,c,n) -> xT (n,b,c) + zero stats --------
__global__ __launch_bounds__(256) void k_transpose(const float* __restrict__ x,
                                                   float* __restrict__ xT,
                                                   int* __restrict__ ncnt,
                                                   float* __restrict__ adjsum) {
    int blk = blockIdx.x;            // grid = B * N/64 = 256
    int tid = threadIdx.x;
    int gtid = blk * 256 + tid;
    if (gtid < NNODES) ncnt[gtid] = 0;
    else if (gtid < 2 * NNODES) adjsum[gtid - NNODES] = 0.f;

    __shared__ float tile[64][65];   // 65-pad: conflict-free transpose
    int b = blk >> 6;
    int n0 = (blk & 63) << 6;
    int tx = tid & 63, ty = tid >> 6;
    const float* xb = x + (size_t)b * CIN * NNODES;
#pragma unroll
    for (int c = ty; c < 64; c += 4)
        tile[c][tx] = xb[(size_t)c * NNODES + n0 + tx];     // coalesced read
    __syncthreads();
#pragma unroll
    for (int n = ty; n < 64; n += 4)                         // 256B row writes
        xT[((size_t)(n0 + n) * BATCH + b) * 64 + tx] = tile[tx][n];
}

// ---------------- k1: bin edges by src + adjsum scatter ---------------------
// Replaces k_main's per-block scan (was 256x redundant: every block streamed
// the full 1MB src/dst array). One pass, edge-parallel, global atomics.
__global__ __launch_bounds__(256) void k_prep(const int* __restrict__ src,
                                              const int* __restrict__ dst,
                                              const float* __restrict__ vals,
                                              int* __restrict__ ncnt,
                                              int* __restrict__ gb,
                                              float* __restrict__ adjsum) {
    int e = blockIdx.x * 256 + threadIdx.x;   // grid = NEDGES/256 exactly
    int s = src[e], d = dst[e];
    int p = atomicAdd(&ncnt[s], 1);
    if (p < CAP) gb[(size_t)s * CAP + p] = d;
    atomicAdd(&adjsum[d], vals[e]);
}

// ---------------- k2: gather + dual-GEMM + epilogue -------------------------
// 256 blocks x 1024 threads; block owns nodes [blk*16, blk*16+16).
// Wave w <-> node nbase+w in BOTH phases, so lists/agg/cnt stay wave-local;
// one __syncthreads total (for the cross-wave W tiles).
__global__ __launch_bounds__(NT, 2) void k_main(
    const float* __restrict__ xT,
    const int* __restrict__ gb,
    const int* __restrict__ ncnt,
    const float* __restrict__ adjsum,
    const float* __restrict__ W,
    const float* __restrict__ bias,
    float* __restrict__ out)
{
    __shared__ float w0s[64][64];        // [c][o], o=63 column zeroed (16KB)
    __shared__ float w1s[64][64];        // 16KB
    __shared__ float agg[NPB][260];      // gathered rows, 260-pad (16.6KB)
    __shared__ int   lists[NPB][CAP];    // per-node dst lists (8KB)

    const int tid   = threadIdx.x;       // 0..1023
    const int nbase = blockIdx.x * NPB;
    const int wv    = tid >> 6;          // wave id = local node id
    const int lane  = tid & 63;
    const int n     = nbase + wv;

    // stage W (cross-wave, needs the barrier below)
    for (int i = tid; i < 64 * 64; i += NT) {
        int c = i >> 6, o = i & 63;
        float v0 = 0.f, v1 = 0.f;
        if (o < COUT) {
            v0 = W[((size_t)o * CIN + c) * 2 + 0];
            v1 = W[((size_t)o * CIN + c) * 2 + 1];
        }
        w0s[c][o] = v0;
        w1s[c][o] = v1;
    }

    // load this wave's neighbor list from its global bucket (coalesced)
    const int cnt = ncnt[n];             // wave-uniform
    const int k1  = min(cnt, CAP);
    for (int k = lane; k < k1; k += 64)
        lists[wv][k] = gb[(size_t)n * CAP + k];

    // gather 1KB xT rows per neighbor (wave-local list, broadcast reads)
    {
        const int* L = lists[wv];
        const float* xb = xT + (size_t)lane * 4;
        float4 acc = make_float4(0.f, 0.f, 0.f, 0.f);
        int k = 0;
        for (; k + 4 <= k1; k += 4) {
            int d0 = L[k], d1 = L[k + 1], d2 = L[k + 2], d3 = L[k + 3];
            float4 v0 = *reinterpret_cast<const float4*>(xb + (size_t)d0 * 256);
            float4 v1 = *reinterpret_cast<const float4*>(xb + (size_t)d1 * 256);
            float4 v2 = *reinterpret_cast<const float4*>(xb + (size_t)d2 * 256);
            float4 v3 = *reinterpret_cast<const float4*>(xb + (size_t)d3 * 256);
            acc.x += (v0.x + v1.x) + (v2.x + v3.x);
            acc.y += (v0.y + v1.y) + (v2.y + v3.y);
            acc.z += (v0.z + v1.z) + (v2.z + v3.z);
            acc.w += (v0.w + v1.w) + (v2.w + v3.w);
        }
        for (; k < k1; ++k) {
            int d = L[k];
            float4 v = *reinterpret_cast<const float4*>(xb + (size_t)d * 256);
            acc.x += v.x; acc.y += v.y; acc.z += v.z; acc.w += v.w;
        }
        *reinterpret_cast<float4*>(&agg[wv][lane * 4]) = acc;
    }
    __syncthreads();                     // W tiles (cross-wave); agg is wave-local

    // dual-GEMM + epilogue: wave wv -> node n, lane = o
    {
        int o = lane;
        float bval = (o < COUT) ? bias[o] : 0.f;
        const float* xrow = xT + (size_t)n * 256;        // wave-uniform row

        float acc0[4] = {0.f, 0.f, 0.f, 0.f};            // W0 . x   per batch
        float acc1[4] = {0.f, 0.f, 0.f, 0.f};            // W1 . agg per batch

#pragma unroll 1
        for (int c4 = 0; c4 < 64; c4 += 4) {
            float w00 = w0s[c4 + 0][o], w01 = w0s[c4 + 1][o];
            float w02 = w0s[c4 + 2][o], w03 = w0s[c4 + 3][o];
            float w10 = w1s[c4 + 0][o], w11 = w1s[c4 + 1][o];
            float w12 = w1s[c4 + 2][o], w13 = w1s[c4 + 3][o];
#pragma unroll
            for (int b = 0; b < 4; ++b) {
                float4 xv = *reinterpret_cast<const float4*>(xrow + b * 64 + c4);
                float4 av = *reinterpret_cast<const float4*>(&agg[wv][b * 64 + c4]);
                acc0[b] += w00 * xv.x + w01 * xv.y + w02 * xv.z + w03 * xv.w;
                acc1[b] += w10 * av.x + w11 * av.y + w12 * av.z + w13 * av.w;
            }
        }

        float dg = (float)cnt;                           // true degree
        float aj = adjsum[n];                            // wave-uniform scalar
        float rd = 1.f / ((aj == 0.f) ? 1.f : aj);
#pragma unroll
        for (int b = 0; b < 4; ++b) {
            float v = (o < COUT) ? (dg * (acc0[b] + bval) + acc1[b]) * rd : aj;
            out[((size_t)(b * 64 + o)) * NNODES + n] = v;   // 16 nodes/block share lines
        }
    }
}

// ---------------- launcher --------------------------------------------------
extern "C" void kernel_launch(void* const* d_in, const int* in_sizes, int n_in,
                              void* d_out, int out_size, void* d_ws, size_t ws_size,
                              hipStream_t stream) {
    const float* x    = (const float*)d_in[0];
    const int*   adj  = (const int*)d_in[1];
    const float* vals = (const float*)d_in[2];
    const float* W    = (const float*)d_in[3];
    const float* bias = (const float*)d_in[4];
    float* out = (float*)d_out;

    const int* src = adj;
    const int* dst = adj + NEDGES;

    char* ws = (char*)d_ws;
    // layout: xT 4MB | gb 2MB | ncnt 16K | adjsum 16K
    float* xT     = (float*)(ws);
    int*   gb     = (int*)  (ws + (4 << 20));
    int*   ncnt   = (int*)  (ws + (6 << 20));
    float* adjsum = (float*)(ws + (6 << 20) + (16 << 10));

    k_transpose<<<BATCH * (NNODES / 64), 256, 0, stream>>>(x, xT, ncnt, adjsum);
    k_prep     <<<NEDGES / 256, 256, 0, stream>>>(src, dst, vals, ncnt, gb, adjsum);
    k_main     <<<NNODES / NPB, NT, 0, stream>>>(xT, gb, ncnt, adjsum, W, bias, out);
}